// Round 1
// baseline (106.951 us; speedup 1.0000x reference)
//
#include <hip/hip_runtime.h>
#include <math.h>

#define NB 16
#define NL 128
#define NP 8192
#define CHUNKS 32
#define CHUNK 256   // p's per block (1 per thread)
#define THREADS 256

__device__ __forceinline__ float fexp2(float x) { return __builtin_amdgcn_exp2f(x); }
__device__ __forceinline__ float frcp(float x)  { return __builtin_amdgcn_rcpf(x); }
__device__ __forceinline__ float frsq(float x)  { return __builtin_amdgcn_rsqf(x); }
__device__ __forceinline__ float fsqrt_(float x){ return __builtin_amdgcn_sqrtf(x); }

// tanh(x) = sign(x) * (1 - e) / (1 + e), e = exp(-2|x|) = exp2(-2*log2(e)*|x|)
__device__ __forceinline__ float ftanh(float x) {
    float t = fexp2(-2.8853900817779268f * fabsf(x));
    float v = (1.0f - t) * frcp(1.0f + t);
    return copysignf(v, x);
}

__global__ __launch_bounds__(THREADS) void physics_main(
    const float* __restrict__ pos_L, const float* __restrict__ pos_P,
    const float* __restrict__ q_L,   const float* __restrict__ q_P,
    const float* __restrict__ x_L,   const float* __restrict__ x_P,
    const float* __restrict__ vdw_radii, const float* __restrict__ eps_tbl,
    float* __restrict__ partial)
{
    const int b     = blockIdx.y;
    const int chunk = blockIdx.x;
    const int tid   = threadIdx.x;

    // ligand tile: per l -> {px,py,pz, 83.015*qL} {radL, sqrt(epsL), x0L, 0}
    __shared__ float4 lig[NL][2];
    __shared__ float red[4][4];

    if (tid < NL) {
        const int base = b * NL + tid;
        float px = pos_L[base * 3 + 0];
        float py = pos_L[base * 3 + 1];
        float pz = pos_L[base * 3 + 2];
        float aq = 83.015f * q_L[base];   // 332.06 / 4
        float rad = 0.0f, ep = 0.0f;
        #pragma unroll
        for (int j = 0; j < 9; ++j) {
            float v = x_L[base * 9 + j];
            rad = fmaf(v, vdw_radii[j], rad);
            ep  = fmaf(v, eps_tbl[j],  ep);
        }
        float seL = fsqrt_(fmaxf(ep, 0.0f));   // relu then sqrt
        float x0  = x_L[base * 9 + 0];
        lig[tid][0] = make_float4(px, py, pz, aq);
        lig[tid][1] = make_float4(rad, seL, x0, 0.0f);
    }
    __syncthreads();

    // protein atom for this thread
    const int p  = chunk * CHUNK + tid;
    const int pb = b * NP + p;
    const float ppx = pos_P[pb * 3 + 0];
    const float ppy = pos_P[pb * 3 + 1];
    const float ppz = pos_P[pb * 3 + 2];
    const float qP  = q_P[pb];
    const float4 xp = ((const float4*)x_P)[pb];
    const float rP  = 1.7f * xp.x + 1.55f * xp.y + 1.52f * xp.z + 1.8f * xp.w;
    const float epP = 0.1f * xp.x + 0.10f * xp.y + 0.15f * xp.z + 0.2f * xp.w;
    const float seP = fsqrt_(epP);
    const float xP0 = xp.x;

    float s1 = 0.0f, s2 = 0.0f, s3 = 0.0f, s4 = 0.0f;

    #pragma unroll 4
    for (int l = 0; l < NL; ++l) {
        const float4 a  = lig[l][0];   // px,py,pz,aq   (LDS broadcast)
        const float4 bv = lig[l][1];   // rad,seL,x0L,-

        float dx = a.x - ppx, dy = a.y - ppy, dz = a.z - ppz;
        float ds = fmaf(dx, dx, fmaf(dy, dy, dz * dz));
        float dsp = ds + 1e-8f;
        float dist = fsqrt_(dsp);

        float sigma = bv.x + rP;
        float sd2 = fmaf(2.0f * sigma, sigma, dsp);     // dist_sq + ALPHA*sigma^2 + 1e-8
        float inv_sd = frsq(sd2);                       // 1/soft_dist

        // electrostatics: 200*tanh(e_raw/200), e_raw = aq*qP/soft_dist
        float er = a.w * qP * inv_sd;
        float e_elec = 200.0f * ftanh(er * 0.005f);

        // vdw
        float ratio = fminf(sigma * inv_sd, 5.0f);
        float r2 = ratio * ratio;
        float r6 = r2 * r2 * r2;
        float eij = bv.y * seP;                          // sqrt(epsL*epsP)
        float ev  = 4.0f * eij * r6 * (r6 - 1.0f);       // e_vdw_raw
        bool posb = (ev >= 0.0f);
        float sc  = posb ? 500.0f : 10.0f;
        float isc = posb ? 0.002f : 0.1f;
        float evg = sc * ftanh(ev * isc);                // e_pos + e_neg
        float lvdw = fminf(fmaxf(ev, -10.0f), 500.0f);   // clip for log path

        // dist mask: sigmoid((12-dist)*2) = 1/(1+exp2(dist*2*log2e - 24*log2e))
        float dmarg = fmaf(dist, 2.8853900817779268f, -34.624680981335122f);
        float dm = frcp(1.0f + fexp2(dmarg));

        s1 = fmaf(e_elec + evg,  dm, s1);
        s4 = fmaf(e_elec + lvdw, dm, s4);

        // hsa: 1/(1+(dist/4)^4) = 1/(1+(ds/16)^2)
        float t  = ds * 0.0625f;
        float hsa = frcp(fmaf(t, t, 1.0f));
        s2 = fmaf(bv.z * xP0, hsa * dm, s2);

        // pauli overlap
        float ov = fmaxf(fmaf(sigma, 0.6f, -dist), 0.0f);
        s3 = fmaf(ov, ov, s3);
    }

    // wave reduce (64 lanes)
    #pragma unroll
    for (int off = 32; off > 0; off >>= 1) {
        s1 += __shfl_down(s1, off);
        s2 += __shfl_down(s2, off);
        s3 += __shfl_down(s3, off);
        s4 += __shfl_down(s4, off);
    }
    const int lane = tid & 63;
    const int wid  = tid >> 6;
    if (lane == 0) {
        red[wid][0] = s1; red[wid][1] = s2; red[wid][2] = s3; red[wid][3] = s4;
    }
    __syncthreads();
    if (tid == 0) {
        float r0 = red[0][0] + red[1][0] + red[2][0] + red[3][0];
        float r1 = red[0][1] + red[1][1] + red[2][1] + red[3][1];
        float r2_ = red[0][2] + red[1][2] + red[2][2] + red[3][2];
        float r3 = red[0][3] + red[1][3] + red[2][3] + red[3][3];
        float* dst = partial + ((size_t)(b * CHUNKS + chunk)) * 4;
        dst[0] = r0; dst[1] = r1; dst[2] = r2_; dst[3] = r3;
    }
}

__global__ void physics_final(const float* __restrict__ partial, float* __restrict__ out)
{
    const int b = threadIdx.x;
    if (b == 0) out[2 * NB] = 2.0f;   // ALPHA
    if (b >= NB) return;
    float s1 = 0.0f, s2 = 0.0f, s3 = 0.0f, s4 = 0.0f;
    for (int c = 0; c < CHUNKS; ++c) {
        const float* src = partial + ((size_t)(b * CHUNKS + c)) * 4;
        s1 += src[0]; s2 += src[1]; s3 += src[2]; s4 += src[3];
    }
    // t_gate = sigmoid(3.0); e_pauli = t_gate*100*sum(overlap^2)
    const float TG100 = 95.25741268224334f;
    float e_pauli = TG100 * s3;
    float e_hsa5  = -2.5f * s2;                 // 5 * (-0.5 * S2)
    float e_raw = s1 + e_hsa5 + e_pauli;
    if (e_raw != e_raw) e_raw = 0.0f;           // nan_to_num
    float e_hard_log = fminf(e_pauli, 10000.0f);
    float e_soft_log = fminf(fmaxf(s4 + e_hsa5, -500.0f), 5000.0f);
    float log_energy = fminf(e_soft_log + e_hard_log, 1000000.0f);

    out[b]          = e_raw;
    out[NB + b]     = e_hard_log;
    out[2 * NB + 1 + b] = log_energy;
}

extern "C" void kernel_launch(void* const* d_in, const int* in_sizes, int n_in,
                              void* d_out, int out_size, void* d_ws, size_t ws_size,
                              hipStream_t stream)
{
    const float* pos_L = (const float*)d_in[0];
    const float* pos_P = (const float*)d_in[1];
    const float* q_L   = (const float*)d_in[2];
    const float* q_P   = (const float*)d_in[3];
    const float* x_L   = (const float*)d_in[4];
    const float* x_P   = (const float*)d_in[5];
    const float* vdw   = (const float*)d_in[6];
    const float* epst  = (const float*)d_in[7];
    float* out = (float*)d_out;
    float* partial = (float*)d_ws;   // 16*32*4 floats = 8 KB

    dim3 grid(CHUNKS, NB);
    physics_main<<<grid, THREADS, 0, stream>>>(pos_L, pos_P, q_L, q_P, x_L, x_P,
                                               vdw, epst, partial);
    physics_final<<<1, 64, 0, stream>>>(partial, out);
}

// Round 2
// 94.393 us; speedup vs baseline: 1.1330x; 1.1330x over previous
//
#include <hip/hip_runtime.h>
#include <math.h>

#define NB 16
#define NL 128
#define NP 8192
#define CHUNKS 32
#define THREADS 256
#define LSPLIT 2
#define LHALF (NL / LSPLIT)   // 64 ligands per block

__device__ __forceinline__ float fexp2(float x) { return __builtin_amdgcn_exp2f(x); }
__device__ __forceinline__ float frcp(float x)  { return __builtin_amdgcn_rcpf(x); }
__device__ __forceinline__ float frsq(float x)  { return __builtin_amdgcn_rsqf(x); }
__device__ __forceinline__ float fsqrt_(float x){ return __builtin_amdgcn_sqrtf(x); }

__global__ __launch_bounds__(THREADS) void physics_main(
    const float* __restrict__ pos_L, const float* __restrict__ pos_P,
    const float* __restrict__ q_L,   const float* __restrict__ q_P,
    const float* __restrict__ x_L,   const float* __restrict__ x_P,
    const float* __restrict__ vdw_radii, const float* __restrict__ eps_tbl,
    float* __restrict__ partial)
{
    const int b     = blockIdx.y;
    const int chunk = blockIdx.x;
    const int z     = blockIdx.z;      // which half of the ligands
    const int tid   = threadIdx.x;

    // ligand tile: {px,py,pz, 83.015*qL} {radL, 4*sqrt(epsL), x0L, 0}
    __shared__ float4 lig[LHALF][2];
    __shared__ float red[4][3];

    if (tid < LHALF) {
        const int base = b * NL + z * LHALF + tid;
        float px = pos_L[base * 3 + 0];
        float py = pos_L[base * 3 + 1];
        float pz = pos_L[base * 3 + 2];
        float aq = 83.015f * q_L[base];   // 332.06 / 4
        float rad = 0.0f, ep = 0.0f;
        #pragma unroll
        for (int j = 0; j < 9; ++j) {
            float v = x_L[base * 9 + j];
            rad = fmaf(v, vdw_radii[j], rad);
            ep  = fmaf(v, eps_tbl[j],  ep);
        }
        float seL4 = 4.0f * fsqrt_(fmaxf(ep, 0.0f));   // 4*sqrt(relu(epsL))
        float x0   = x_L[base * 9 + 0];
        lig[tid][0] = make_float4(px, py, pz, aq);
        lig[tid][1] = make_float4(rad, seL4, x0, 0.0f);
    }
    __syncthreads();

    // protein atom for this thread
    const int p  = chunk * THREADS + tid;
    const int pb = b * NP + p;
    const float ppx = pos_P[pb * 3 + 0];
    const float ppy = pos_P[pb * 3 + 1];
    const float ppz = pos_P[pb * 3 + 2];
    const float qP  = q_P[pb];
    const float4 xp = ((const float4*)x_P)[pb];
    const float rP  = 1.7f * xp.x + 1.55f * xp.y + 1.52f * xp.z + 1.8f * xp.w;
    const float epP = 0.1f * xp.x + 0.10f * xp.y + 0.15f * xp.z + 0.2f * xp.w;
    const float seP = fsqrt_(epP);
    const float xP0 = xp.x;

    float s1 = 0.0f, s2 = 0.0f, s3 = 0.0f;

    #pragma unroll 4
    for (int l = 0; l < LHALF; ++l) {
        const float4 a  = lig[l][0];   // px,py,pz,aq   (LDS broadcast)
        const float4 bv = lig[l][1];   // rad, 4*sqrt(epsL), x0L, -

        float dx = a.x - ppx, dy = a.y - ppy, dz = a.z - ppz;
        // seed with the reference's 1e-8 (it appears in BOTH dist and soft_dist)
        float ds = fmaf(dx, dx, fmaf(dy, dy, fmaf(dz, dz, 1e-8f)));
        float dist = fsqrt_(ds);

        float sigma = bv.x + rP;
        float sd2 = fmaf(sigma, sigma + sigma, ds);     // ds + 2*sigma^2
        float inv_sd = frsq(sd2);                       // 1/soft_dist

        // electrostatics: 200*tanh(v/200), |v/200| <= 0.16 -> 5th-order poly
        float v  = (a.w * qP) * inv_sd;                 // e_elec_raw
        float u  = 0.005f * v;
        float u2 = u * u;
        float pf = fmaf(u2, fmaf(u2, 0.13333333f, -0.33333333f), 1.0f);
        float e_elec = v * pf;

        // vdw: ratio <= 1/sqrt(2) always -> e_vdw_raw in [-0.14, 0];
        // tanh(ev/10)*10 == ev to 9e-6, and the log-path clip is dead,
        // so the grad path and log path share the same addend.
        float ratio = sigma * inv_sd;
        float r2 = ratio * ratio;
        float r6 = r2 * r2 * r2;
        float ev = (bv.y * seP) * r6 * (r6 - 1.0f);     // 4*eps_ij*(r12-r6)
        float addend = e_elec + ev;

        // dm = sigmoid((12-dist)*2); hsa = 1/(1+(ds/16)^2); one rcp for both
        float m  = fminf(fmaf(dist, 2.8853901f, -34.624681f), 30.0f);
        float A  = 1.0f + fexp2(m);
        float tq = ds * 0.0625f;
        float Bh = fmaf(tq, tq, 1.0f);
        float r  = frcp(A * Bh);                        // = hsa * dm
        float dm = Bh * r;

        s1 = fmaf(addend, dm, s1);
        s2 = fmaf(bv.z, r, s2);                         // * xP0 hoisted out

        float ov = fmaxf(fmaf(sigma, 0.6f, -dist), 0.0f);
        s3 = fmaf(ov, ov, s3);
    }
    s2 *= xP0;

    // wave reduce (64 lanes)
    #pragma unroll
    for (int off = 32; off > 0; off >>= 1) {
        s1 += __shfl_down(s1, off);
        s2 += __shfl_down(s2, off);
        s3 += __shfl_down(s3, off);
    }
    const int lane = tid & 63;
    const int wid  = tid >> 6;
    if (lane == 0) {
        red[wid][0] = s1; red[wid][1] = s2; red[wid][2] = s3;
    }
    __syncthreads();
    if (tid == 0) {
        float r0 = red[0][0] + red[1][0] + red[2][0] + red[3][0];
        float r1 = red[0][1] + red[1][1] + red[2][1] + red[3][1];
        float r2_ = red[0][2] + red[1][2] + red[2][2] + red[3][2];
        float* dst = partial + ((size_t)((b * CHUNKS + chunk) * LSPLIT + z)) * 4;
        dst[0] = r0; dst[1] = r1; dst[2] = r2_;
    }
}

__global__ void physics_final(const float* __restrict__ partial, float* __restrict__ out)
{
    const int b = threadIdx.x;
    if (b == 0) out[2 * NB] = 2.0f;   // ALPHA
    if (b >= NB) return;
    float s1 = 0.0f, s2 = 0.0f, s3 = 0.0f;
    for (int c = 0; c < CHUNKS * LSPLIT; ++c) {
        const float* src = partial + ((size_t)(b * CHUNKS * LSPLIT + c)) * 4;
        s1 += src[0]; s2 += src[1]; s3 += src[2];
    }
    // t_gate = sigmoid(3.0); e_pauli = t_gate*100*sum(overlap^2)
    const float TG100 = 95.25741268224334f;
    float e_pauli = TG100 * s3;
    float e_hsa5  = -2.5f * s2;                 // 5 * (-0.5 * S2)
    float e_raw = s1 + e_hsa5 + e_pauli;
    if (e_raw != e_raw) e_raw = 0.0f;           // nan_to_num
    float e_hard_log = fminf(e_pauli, 10000.0f);
    float e_soft_log = fminf(fmaxf(s1 + e_hsa5, -500.0f), 5000.0f);  // s4 == s1
    float log_energy = fminf(e_soft_log + e_hard_log, 1000000.0f);

    out[b]              = e_raw;
    out[NB + b]         = e_hard_log;
    out[2 * NB + 1 + b] = log_energy;
}

extern "C" void kernel_launch(void* const* d_in, const int* in_sizes, int n_in,
                              void* d_out, int out_size, void* d_ws, size_t ws_size,
                              hipStream_t stream)
{
    const float* pos_L = (const float*)d_in[0];
    const float* pos_P = (const float*)d_in[1];
    const float* q_L   = (const float*)d_in[2];
    const float* q_P   = (const float*)d_in[3];
    const float* x_L   = (const float*)d_in[4];
    const float* x_P   = (const float*)d_in[5];
    const float* vdw   = (const float*)d_in[6];
    const float* epst  = (const float*)d_in[7];
    float* out = (float*)d_out;
    float* partial = (float*)d_ws;   // 16*32*2*4 floats = 16 KB

    dim3 grid(CHUNKS, NB, LSPLIT);
    physics_main<<<grid, THREADS, 0, stream>>>(pos_L, pos_P, q_L, q_P, x_L, x_P,
                                               vdw, epst, partial);
    physics_final<<<1, 64, 0, stream>>>(partial, out);
}

// Round 3
// 92.038 us; speedup vs baseline: 1.1620x; 1.0256x over previous
//
#include <hip/hip_runtime.h>
#include <math.h>

#define NB 16
#define NL 128
#define NP 8192
#define CHUNKS 32
#define THREADS 256
#define LSPLIT 4
#define LHALF (NL / LSPLIT)     // 32 ligands per block
#define LPAIR (LHALF / 2)       // 16 packed pairs

typedef float v2 __attribute__((ext_vector_type(2)));

__device__ __forceinline__ float fexp2(float x) { return __builtin_amdgcn_exp2f(x); }
__device__ __forceinline__ float frcp(float x)  { return __builtin_amdgcn_rcpf(x); }
__device__ __forceinline__ float frsq(float x)  { return __builtin_amdgcn_rsqf(x); }
__device__ __forceinline__ float fsqrt_(float x){ return __builtin_amdgcn_sqrtf(x); }
__device__ __forceinline__ v2 vfma(v2 a, v2 b, v2 c) { return __builtin_elementwise_fma(a, b, c); }

__global__ __launch_bounds__(THREADS) void physics_main(
    const float* __restrict__ pos_L, const float* __restrict__ pos_P,
    const float* __restrict__ q_L,   const float* __restrict__ q_P,
    const float* __restrict__ x_L,   const float* __restrict__ x_P,
    const float* __restrict__ vdw_radii, const float* __restrict__ eps_tbl,
    float* __restrict__ partial)
{
    const int b     = blockIdx.y;
    const int chunk = blockIdx.x;
    const int z     = blockIdx.z;
    const int tid   = threadIdx.x;

    // packed ligand tile, SoA-of-pairs:
    // lig[i][0] = (px0,px1,py0,py1)  lig[i][1] = (pz0,pz1,aq0,aq1)
    // lig[i][2] = (rad0,rad1,se0,se1)  lig3[i] = (x00,x01)
    __shared__ float4 lig[LPAIR][3];
    __shared__ float2 lig3[LPAIR];
    __shared__ float red[4][3];

    if (tid < LHALF) {
        const int base = b * NL + z * LHALF + tid;
        float px = pos_L[base * 3 + 0];
        float py = pos_L[base * 3 + 1];
        float pz = pos_L[base * 3 + 2];
        float aq = 83.015f * q_L[base];   // 332.06 / 4
        float rad = 0.0f, ep = 0.0f;
        #pragma unroll
        for (int j = 0; j < 9; ++j) {
            float v = x_L[base * 9 + j];
            rad = fmaf(v, vdw_radii[j], rad);
            ep  = fmaf(v, eps_tbl[j],  ep);
        }
        float se4 = 4.0f * fsqrt_(fmaxf(ep, 0.0f));   // 4*sqrt(relu(epsL))
        float x0  = x_L[base * 9 + 0];
        const int i = tid >> 1, s = tid & 1;
        float* L = (float*)lig;
        L[i * 12 + 0 + s] = px;
        L[i * 12 + 2 + s] = py;
        L[i * 12 + 4 + s] = pz;
        L[i * 12 + 6 + s] = aq;
        L[i * 12 + 8 + s] = rad;
        L[i * 12 + 10 + s] = se4;
        ((float*)lig3)[i * 2 + s] = x0;
    }
    __syncthreads();

    const int p  = chunk * THREADS + tid;
    const int pb = b * NP + p;
    const float ppx = pos_P[pb * 3 + 0];
    const float ppy = pos_P[pb * 3 + 1];
    const float ppz = pos_P[pb * 3 + 2];
    const float qP  = q_P[pb];
    const float4 xp = ((const float4*)x_P)[pb];
    const float rP  = 1.7f * xp.x + 1.55f * xp.y + 1.52f * xp.z + 1.8f * xp.w;
    const float epP = 0.1f * xp.x + 0.10f * xp.y + 0.15f * xp.z + 0.2f * xp.w;
    const float seP = fsqrt_(epP);
    const float xP0 = xp.x;

    v2 s1v = (v2)0.0f, s2v = (v2)0.0f, s3v = (v2)0.0f;
    const v2 onev = (v2)1.0f;
    const v2 C1 = (v2)(-8.3333333e-6f);   // -1/(3*200^2)
    const v2 C2 = (v2)(8.3333333e-11f);   //  2/(15*200^4)

    #pragma unroll 4
    for (int i = 0; i < LPAIR; ++i) {
        const float4 t0 = lig[i][0];
        const float4 t1 = lig[i][1];
        const float4 t2 = lig[i][2];
        const float2 t3 = lig3[i];

        v2 lx; lx.x = t0.x; lx.y = t0.y;
        v2 ly; ly.x = t0.z; ly.y = t0.w;
        v2 lz; lz.x = t1.x; lz.y = t1.y;
        v2 laq; laq.x = t1.z; laq.y = t1.w;
        v2 lrad; lrad.x = t2.x; lrad.y = t2.y;
        v2 lse; lse.x = t2.z; lse.y = t2.w;
        v2 lx0; lx0.x = t3.x; lx0.y = t3.y;

        v2 dx = lx - ppx, dy = ly - ppy, dz = lz - ppz;
        v2 ds = vfma(dx, dx, vfma(dy, dy, vfma(dz, dz, (v2)1e-8f)));
        v2 dist; dist.x = fsqrt_(ds.x); dist.y = fsqrt_(ds.y);

        v2 sigma = lrad + rP;
        v2 sigsq = sigma * sigma;
        v2 sd2 = vfma(sigsq, (v2)2.0f, ds);           // ds + 2*sigma^2
        v2 inv; inv.x = frsq(sd2.x); inv.y = frsq(sd2.y);

        // e_elec = 200*tanh(v/200) ~= v*(1 + v^2*(C1 + v^2*C2))
        v2 v = laq * (qP * inv);
        v2 w = v * v;
        v2 pf = vfma(w, vfma(w, C2, C1), onev);
        v2 e_elec = v * pf;

        // e_vdw_raw: always in [-0.14, 0] -> grad path == log path == ev
        v2 r2 = sigsq * (inv * inv);
        v2 r6 = r2 * r2 * r2;
        v2 t126 = vfma(r6, r6, -r6);                  // r12 - r6
        v2 ev = (lse * seP) * t126;                   // 4*eps_ij*(r12-r6)
        v2 addend = e_elec + ev;

        // dm = sigmoid((12-dist)*2); hsa = 1/(1+(ds/16)^2); one rcp for both.
        // exp2 overflow -> A=inf -> r=0 -> dm=0: correct limit, no NaN.
        v2 m = vfma(dist, (v2)2.8853901f, (v2)(-34.624681f));
        v2 A; A.x = fexp2(m.x); A.y = fexp2(m.y);
        A = A + onev;
        v2 tq = ds * 0.0625f;
        v2 Bh = vfma(tq, tq, onev);
        v2 AB = A * Bh;
        v2 r; r.x = frcp(AB.x); r.y = frcp(AB.y);
        v2 dm = Bh * r;

        s1v = vfma(addend, dm, s1v);
        s2v = vfma(lx0, r, s2v);
        v2 ov = __builtin_elementwise_max(vfma(sigma, (v2)0.6f, -dist), (v2)0.0f);
        s3v = vfma(ov, ov, s3v);
    }

    float s1 = s1v.x + s1v.y;
    float s2 = (s2v.x + s2v.y) * xP0;
    float s3 = s3v.x + s3v.y;

    #pragma unroll
    for (int off = 32; off > 0; off >>= 1) {
        s1 += __shfl_down(s1, off);
        s2 += __shfl_down(s2, off);
        s3 += __shfl_down(s3, off);
    }
    const int lane = tid & 63;
    const int wid  = tid >> 6;
    if (lane == 0) {
        red[wid][0] = s1; red[wid][1] = s2; red[wid][2] = s3;
    }
    __syncthreads();
    if (tid == 0) {
        float r0 = red[0][0] + red[1][0] + red[2][0] + red[3][0];
        float r1 = red[0][1] + red[1][1] + red[2][1] + red[3][1];
        float r2_ = red[0][2] + red[1][2] + red[2][2] + red[3][2];
        float* dst = partial + ((size_t)((b * CHUNKS + chunk) * LSPLIT + z)) * 4;
        dst[0] = r0; dst[1] = r1; dst[2] = r2_;
    }
}

__global__ void physics_final(const float* __restrict__ partial, float* __restrict__ out)
{
    const int b = threadIdx.x;
    if (b == 0) out[2 * NB] = 2.0f;   // ALPHA
    if (b >= NB) return;
    float s1 = 0.0f, s2 = 0.0f, s3 = 0.0f;
    #pragma unroll 8
    for (int c = 0; c < CHUNKS * LSPLIT; ++c) {
        const float* src = partial + ((size_t)(b * CHUNKS * LSPLIT + c)) * 4;
        s1 += src[0]; s2 += src[1]; s3 += src[2];
    }
    const float TG100 = 95.25741268224334f;   // sigmoid(3)*100
    float e_pauli = TG100 * s3;
    float e_hsa5  = -2.5f * s2;               // 5 * (-0.5 * S2)
    float e_raw = s1 + e_hsa5 + e_pauli;
    if (e_raw != e_raw) e_raw = 0.0f;
    float e_hard_log = fminf(e_pauli, 10000.0f);
    float e_soft_log = fminf(fmaxf(s1 + e_hsa5, -500.0f), 5000.0f);  // s4 == s1
    float log_energy = fminf(e_soft_log + e_hard_log, 1000000.0f);

    out[b]              = e_raw;
    out[NB + b]         = e_hard_log;
    out[2 * NB + 1 + b] = log_energy;
}

extern "C" void kernel_launch(void* const* d_in, const int* in_sizes, int n_in,
                              void* d_out, int out_size, void* d_ws, size_t ws_size,
                              hipStream_t stream)
{
    const float* pos_L = (const float*)d_in[0];
    const float* pos_P = (const float*)d_in[1];
    const float* q_L   = (const float*)d_in[2];
    const float* q_P   = (const float*)d_in[3];
    const float* x_L   = (const float*)d_in[4];
    const float* x_P   = (const float*)d_in[5];
    const float* vdw   = (const float*)d_in[6];
    const float* epst  = (const float*)d_in[7];
    float* out = (float*)d_out;
    float* partial = (float*)d_ws;   // 16*32*4*4 floats = 32 KB

    dim3 grid(CHUNKS, NB, LSPLIT);
    physics_main<<<grid, THREADS, 0, stream>>>(pos_L, pos_P, q_L, q_P, x_L, x_P,
                                               vdw, epst, partial);
    physics_final<<<1, 64, 0, stream>>>(partial, out);
}

// Round 4
// 91.732 us; speedup vs baseline: 1.1659x; 1.0033x over previous
//
#include <hip/hip_runtime.h>
#include <math.h>

#define NB 16
#define NL 128
#define NP 8192
#define CHUNKS 32        // 8192 / 256 protein atoms per block
#define THREADS 256
#define LSPLIT 4         // ligand splits -> grid z
#define LPB 16           // ligand PAIRS per block = 128/4/2
#define NPAIR 64         // ligand pairs per batch

typedef float v2 __attribute__((ext_vector_type(2)));

__device__ __forceinline__ float fexp2(float x) { return __builtin_amdgcn_exp2f(x); }
__device__ __forceinline__ float frcp(float x)  { return __builtin_amdgcn_rcpf(x); }
__device__ __forceinline__ float frsq(float x)  { return __builtin_amdgcn_rsqf(x); }
__device__ __forceinline__ float fsqrt_(float x){ return __builtin_amdgcn_sqrtf(x); }
__device__ __forceinline__ v2 vfma(v2 a, v2 b, v2 c) { return __builtin_elementwise_fma(a, b, c); }

// ---- kernel 1: precompute ligand features into pair-interleaved layout ----
// per pair (64B): [px0,px1, py0,py1, pz0,pz1, aq0,aq1, rad0,rad1, se0,se1, x00,x01, 0,0]
__global__ __launch_bounds__(256) void lig_prep(
    const float* __restrict__ pos_L, const float* __restrict__ q_L,
    const float* __restrict__ x_L,
    const float* __restrict__ vdw_radii, const float* __restrict__ eps_tbl,
    float* __restrict__ ligbuf)
{
    const int id = blockIdx.x * 256 + threadIdx.x;
    if (id >= NB * NL) return;
    const int b = id >> 7, l = id & 127;
    const int base = b * NL + l;
    float px = pos_L[base * 3 + 0];
    float py = pos_L[base * 3 + 1];
    float pz = pos_L[base * 3 + 2];
    float aq = 83.015f * q_L[base];       // 332.06 / 4
    float rad = 0.0f, ep = 0.0f;
    #pragma unroll
    for (int j = 0; j < 9; ++j) {
        float v = x_L[base * 9 + j];
        rad = fmaf(v, vdw_radii[j], rad);
        ep  = fmaf(v, eps_tbl[j],  ep);
    }
    float se4 = 4.0f * fsqrt_(fmaxf(ep, 0.0f));   // 4*sqrt(relu(epsL))
    float x0  = x_L[base * 9 + 0];
    const int pair = l >> 1, s = l & 1;
    float* dst = ligbuf + ((size_t)(b * NPAIR + pair)) * 16;
    dst[ 0 + s] = px;
    dst[ 2 + s] = py;
    dst[ 4 + s] = pz;
    dst[ 6 + s] = aq;
    dst[ 8 + s] = rad;
    dst[10 + s] = se4;
    dst[12 + s] = x0;
    dst[14 + s] = 0.0f;
}

// ---- kernel 2: main pairwise loop. Ligand pairs come in via uniform (SMEM)
// loads -> SGPR pairs feeding v_pk ops; protein per-lane scalars splatted to
// VGPR pairs once. No LDS / no barriers in the hot loop. ----
__global__ __launch_bounds__(THREADS) void physics_main(
    const float* __restrict__ pos_P, const float* __restrict__ q_P,
    const float* __restrict__ x_P,   const float* __restrict__ ligbuf,
    float* __restrict__ partial)
{
    const int b     = blockIdx.y;
    const int chunk = blockIdx.x;
    const int z     = blockIdx.z;
    const int tid   = threadIdx.x;

    __shared__ float red[4][3];

    const int pb = b * NP + chunk * THREADS + tid;
    const float ppx = pos_P[pb * 3 + 0];
    const float ppy = pos_P[pb * 3 + 1];
    const float ppz = pos_P[pb * 3 + 2];
    const float qP  = q_P[pb];
    const float4 xp = ((const float4*)x_P)[pb];
    const float rP  = 1.7f * xp.x + 1.55f * xp.y + 1.52f * xp.z + 1.8f * xp.w;
    const float epP = 0.1f * xp.x + 0.10f * xp.y + 0.15f * xp.z + 0.2f * xp.w;
    const float seP = fsqrt_(epP);
    const float xP0 = xp.x;

    // loop-invariant splats (live in VGPR pairs)
    v2 ppx2; ppx2.x = ppx; ppx2.y = ppx;
    v2 ppy2; ppy2.x = ppy; ppy2.y = ppy;
    v2 ppz2; ppz2.x = ppz; ppz2.y = ppz;
    v2 qP2;  qP2.x  = qP;  qP2.y  = qP;
    v2 rP2;  rP2.x  = rP;  rP2.y  = rP;
    v2 seP2; seP2.x = seP; seP2.y = seP;
    const v2 onev = (v2)1.0f;
    const v2 C1 = (v2)(-8.3333333e-6f);   // -1/(3*200^2)
    const v2 C2 = (v2)(8.3333333e-11f);   //  2/(15*200^4)
    const v2 K1 = (v2)(2.8853901f);       // 2*log2(e)
    const v2 K2 = (v2)(-34.624681f);      // -24*log2(e)
    const v2 KQ = (v2)(0.0625f);
    const v2 KO = (v2)(0.6f);

    v2 s1v = (v2)0.0f, s2v = (v2)0.0f, s3v = (v2)0.0f;

    const float* lp = ligbuf + ((size_t)(b * NPAIR + z * LPB)) * 16;

    #pragma unroll 4
    for (int i = 0; i < LPB; ++i) {
        const v2* L = (const v2*)(lp + i * 16);   // uniform -> s_load
        v2 lx = L[0], ly = L[1], lz = L[2], laq = L[3];
        v2 lrad = L[4], lse = L[5], lx0 = L[6];

        v2 dx = lx - ppx2, dy = ly - ppy2, dz = lz - ppz2;
        v2 ds = vfma(dx, dx, vfma(dy, dy, vfma(dz, dz, (v2)1e-8f)));
        v2 dist; dist.x = fsqrt_(ds.x); dist.y = fsqrt_(ds.y);

        v2 sigma = lrad + rP2;
        v2 sigsq = sigma * sigma;
        v2 sd2 = vfma(sigsq, (v2)2.0f, ds);         // ds + 2*sigma^2
        v2 inv; inv.x = frsq(sd2.x); inv.y = frsq(sd2.y);

        // e_elec = 200*tanh(v/200) ~= v*(1 + v^2*(C1 + v^2*C2)), |v|<=32
        v2 v = (laq * qP2) * inv;
        v2 w = v * v;
        v2 pf = vfma(w, vfma(w, C2, C1), onev);
        v2 e_elec = v * pf;

        // e_vdw_raw in [-0.14,0] always -> grad path == clipped log path == ev
        v2 inv2 = inv * inv;
        v2 r2 = sigsq * inv2;
        v2 r6 = r2 * r2 * r2;
        v2 t126 = vfma(r6, r6, -r6);                // r12 - r6
        v2 ev = (lse * seP2) * t126;                // 4*eps_ij*(r12-r6)
        v2 addend = e_elec + ev;

        // dm = sigmoid((12-dist)*2); hsa = 1/(1+(ds/16)^2); shared rcp.
        // exp2 overflow -> A=inf -> r=0 -> dm=0 (correct limit, no NaN).
        v2 m = vfma(dist, K1, K2);
        v2 A; A.x = fexp2(m.x); A.y = fexp2(m.y);
        A = A + onev;
        v2 tq = ds * KQ;
        v2 Bh = vfma(tq, tq, onev);
        v2 AB = A * Bh;
        v2 r; r.x = frcp(AB.x); r.y = frcp(AB.y);
        v2 dm = Bh * r;

        s1v = vfma(addend, dm, s1v);
        s2v = vfma(lx0, r, s2v);
        v2 ov = __builtin_elementwise_max(vfma(sigma, KO, -dist), (v2)0.0f);
        s3v = vfma(ov, ov, s3v);
    }

    float s1 = s1v.x + s1v.y;
    float s2 = (s2v.x + s2v.y) * xP0;
    float s3 = s3v.x + s3v.y;

    #pragma unroll
    for (int off = 32; off > 0; off >>= 1) {
        s1 += __shfl_down(s1, off);
        s2 += __shfl_down(s2, off);
        s3 += __shfl_down(s3, off);
    }
    const int lane = tid & 63;
    const int wid  = tid >> 6;
    if (lane == 0) { red[wid][0] = s1; red[wid][1] = s2; red[wid][2] = s3; }
    __syncthreads();
    if (tid == 0) {
        float r0 = red[0][0] + red[1][0] + red[2][0] + red[3][0];
        float r1 = red[0][1] + red[1][1] + red[2][1] + red[3][1];
        float r2_ = red[0][2] + red[1][2] + red[2][2] + red[3][2];
        float* dst = partial + ((size_t)((b * CHUNKS + chunk) * LSPLIT + z)) * 4;
        dst[0] = r0; dst[1] = r1; dst[2] = r2_;
    }
}

// ---- kernel 3: finalize. 256 threads: 16 lanes per batch, shfl within
// 16-lane groups. ----
__global__ __launch_bounds__(256) void physics_final(
    const float* __restrict__ partial, float* __restrict__ out)
{
    const int tid = threadIdx.x;
    if (tid == 0) out[2 * NB] = 2.0f;   // ALPHA
    const int b = tid >> 4;
    const int j = tid & 15;
    float s1 = 0.0f, s2 = 0.0f, s3 = 0.0f;
    const int NPART = CHUNKS * LSPLIT;   // 128 per batch
    #pragma unroll
    for (int k = 0; k < NPART / 16; ++k) {
        const float* src = partial + ((size_t)(b * NPART + j * (NPART / 16) + k)) * 4;
        s1 += src[0]; s2 += src[1]; s3 += src[2];
    }
    #pragma unroll
    for (int off = 8; off > 0; off >>= 1) {
        s1 += __shfl_down(s1, off, 16);
        s2 += __shfl_down(s2, off, 16);
        s3 += __shfl_down(s3, off, 16);
    }
    if (j == 0) {
        const float TG100 = 95.25741268224334f;   // sigmoid(3)*100
        float e_pauli = TG100 * s3;
        float e_hsa5  = -2.5f * s2;               // 5 * (-0.5 * S2)
        float e_raw = s1 + e_hsa5 + e_pauli;
        if (e_raw != e_raw) e_raw = 0.0f;
        float e_hard_log = fminf(e_pauli, 10000.0f);
        float e_soft_log = fminf(fmaxf(s1 + e_hsa5, -500.0f), 5000.0f);  // s4==s1
        float log_energy = fminf(e_soft_log + e_hard_log, 1000000.0f);
        out[b]              = e_raw;
        out[NB + b]         = e_hard_log;
        out[2 * NB + 1 + b] = log_energy;
    }
}

extern "C" void kernel_launch(void* const* d_in, const int* in_sizes, int n_in,
                              void* d_out, int out_size, void* d_ws, size_t ws_size,
                              hipStream_t stream)
{
    const float* pos_L = (const float*)d_in[0];
    const float* pos_P = (const float*)d_in[1];
    const float* q_L   = (const float*)d_in[2];
    const float* q_P   = (const float*)d_in[3];
    const float* x_L   = (const float*)d_in[4];
    const float* x_P   = (const float*)d_in[5];
    const float* vdw   = (const float*)d_in[6];
    const float* epst  = (const float*)d_in[7];
    float* out = (float*)d_out;

    float* ligbuf  = (float*)d_ws;                       // 16*64*16 floats = 64 KB
    float* partial = ligbuf + (size_t)NB * NPAIR * 16;   // 16*128*4 floats = 32 KB

    lig_prep<<<8, 256, 0, stream>>>(pos_L, q_L, x_L, vdw, epst, ligbuf);
    dim3 grid(CHUNKS, NB, LSPLIT);
    physics_main<<<grid, THREADS, 0, stream>>>(pos_P, q_P, x_P, ligbuf, partial);
    physics_final<<<1, 256, 0, stream>>>(partial, out);
}

// Round 5
// 91.293 us; speedup vs baseline: 1.1715x; 1.0048x over previous
//
#include <hip/hip_runtime.h>
#include <math.h>
#include <stdint.h>

#define NB 16
#define NL 128
#define NP 8192
#define CHUNKS 32        // 8192 / 256 protein atoms per block
#define THREADS 256
#define LSPLIT 4         // ligand splits -> grid z
#define LPB 16           // ligand PAIRS per block = 128/4/2
#define NPAIR 64         // ligand pairs per batch

typedef float v2 __attribute__((ext_vector_type(2)));
typedef float v4 __attribute__((ext_vector_type(4)));
// constant address space -> guaranteed scalar (SMEM) loads for uniform addrs
typedef const __attribute__((address_space(4))) v4* cv4p;

__device__ __forceinline__ float fexp2(float x) { return __builtin_amdgcn_exp2f(x); }
__device__ __forceinline__ float frcp(float x)  { return __builtin_amdgcn_rcpf(x); }
__device__ __forceinline__ float frsq(float x)  { return __builtin_amdgcn_rsqf(x); }
__device__ __forceinline__ float fsqrt_(float x){ return __builtin_amdgcn_sqrtf(x); }
__device__ __forceinline__ v2 vfma(v2 a, v2 b, v2 c) { return __builtin_elementwise_fma(a, b, c); }

// ---- kernel 1: ligand features, pair-interleaved 64B records ----
// [px0,px1, py0,py1 | pz0,pz1, aq0,aq1 | rad0,rad1, se0,se1 | x00,x01, 0,0]
__global__ __launch_bounds__(256) void lig_prep(
    const float* __restrict__ pos_L, const float* __restrict__ q_L,
    const float* __restrict__ x_L,
    const float* __restrict__ vdw_radii, const float* __restrict__ eps_tbl,
    float* __restrict__ ligbuf)
{
    const int id = blockIdx.x * 256 + threadIdx.x;
    if (id >= NB * NL) return;
    const int b = id >> 7, l = id & 127;
    const int base = b * NL + l;
    float px = pos_L[base * 3 + 0];
    float py = pos_L[base * 3 + 1];
    float pz = pos_L[base * 3 + 2];
    float aq = 83.015f * q_L[base];       // 332.06 / 4
    float rad = 0.0f, ep = 0.0f;
    #pragma unroll
    for (int j = 0; j < 9; ++j) {
        float v = x_L[base * 9 + j];
        rad = fmaf(v, vdw_radii[j], rad);
        ep  = fmaf(v, eps_tbl[j],  ep);
    }
    float se4 = 4.0f * fsqrt_(fmaxf(ep, 0.0f));   // 4*sqrt(relu(epsL))
    float x0  = x_L[base * 9 + 0];
    const int pair = l >> 1, s = l & 1;
    float* dst = ligbuf + ((size_t)(b * NPAIR + pair)) * 16;
    dst[ 0 + s] = px;
    dst[ 2 + s] = py;
    dst[ 4 + s] = pz;
    dst[ 6 + s] = aq;
    dst[ 8 + s] = rad;
    dst[10 + s] = se4;
    dst[12 + s] = x0;
    dst[14 + s] = 0.0f;
}

// ---- kernel 2: main pairwise loop; ligand data via SMEM (s_load), fully
// unrolled; protein per-lane state in VGPRs; no LDS/barriers in loop ----
__global__ __launch_bounds__(THREADS) void physics_main(
    const float* __restrict__ pos_P, const float* __restrict__ q_P,
    const float* __restrict__ x_P,   const float* __restrict__ ligbuf,
    float* __restrict__ partial)
{
    const int b     = blockIdx.y;
    const int chunk = blockIdx.x;
    const int z     = blockIdx.z;
    const int tid   = threadIdx.x;

    __shared__ float red[4][3];

    const int pb = b * NP + chunk * THREADS + tid;
    const float ppx = pos_P[pb * 3 + 0];
    const float ppy = pos_P[pb * 3 + 1];
    const float ppz = pos_P[pb * 3 + 2];
    const float qP  = q_P[pb];
    const float4 xp = ((const float4*)x_P)[pb];
    const float rP  = 1.7f * xp.x + 1.55f * xp.y + 1.52f * xp.z + 1.8f * xp.w;
    const float epP = 0.1f * xp.x + 0.10f * xp.y + 0.15f * xp.z + 0.2f * xp.w;
    const float seP = fsqrt_(epP);
    const float xP0 = xp.x;

    v2 ppx2; ppx2.x = ppx; ppx2.y = ppx;
    v2 ppy2; ppy2.x = ppy; ppy2.y = ppy;
    v2 ppz2; ppz2.x = ppz; ppz2.y = ppz;
    v2 qP2;  qP2.x  = qP;  qP2.y  = qP;
    v2 rP2;  rP2.x  = rP;  rP2.y  = rP;
    v2 seP2; seP2.x = seP; seP2.y = seP;
    const v2 onev = (v2)1.0f;
    const v2 C1 = (v2)(-8.3333333e-6f);   // -1/(3*200^2): 200*tanh(v/200)~v*(1+C1*v^2)
    const v2 K1 = (v2)(2.8853901f);       // 2*log2(e)
    const v2 K2 = (v2)(-34.624681f);      // -24*log2(e)
    const v2 KQ = (v2)(0.0625f);
    const v2 KO = (v2)(0.6f);

    v2 s1v = (v2)0.0f, s2v = (v2)0.0f, s3v = (v2)0.0f;

    const float* lp = ligbuf + ((size_t)(b * NPAIR + z * LPB)) * 16;
    cv4p Lc = (cv4p)(uintptr_t)lp;        // force SMEM path

    #pragma unroll
    for (int i = 0; i < LPB; ++i) {
        const v4 A0 = Lc[i * 4 + 0];      // px0,px1,py0,py1
        const v4 A1 = Lc[i * 4 + 1];      // pz0,pz1,aq0,aq1
        const v4 A2 = Lc[i * 4 + 2];      // rad0,rad1,se0,se1
        const v4 A3 = Lc[i * 4 + 3];      // x00,x01,-,-

        v2 lx;   lx.x = A0.x;   lx.y = A0.y;
        v2 ly;   ly.x = A0.z;   ly.y = A0.w;
        v2 lz;   lz.x = A1.x;   lz.y = A1.y;
        v2 laq;  laq.x = A1.z;  laq.y = A1.w;
        v2 lrad; lrad.x = A2.x; lrad.y = A2.y;
        v2 lse;  lse.x = A2.z;  lse.y = A2.w;
        v2 lx0;  lx0.x = A3.x;  lx0.y = A3.y;

        v2 dx = lx - ppx2, dy = ly - ppy2, dz = lz - ppz2;
        v2 ds = vfma(dx, dx, vfma(dy, dy, vfma(dz, dz, (v2)1e-8f)));
        v2 dist; dist.x = fsqrt_(ds.x); dist.y = fsqrt_(ds.y);

        v2 sigma = lrad + rP2;
        v2 sigsq = sigma * sigma;
        v2 sd2 = vfma(sigsq, (v2)2.0f, ds);         // ds + 2*sigma^2
        v2 inv; inv.x = frsq(sd2.x); inv.y = frsq(sd2.y);

        // e_elec = 200*tanh(v/200) ~ v*(1 + C1*v^2); |v|<=32 -> err<=1.4e-3
        v2 v = (laq * qP2) * inv;
        v2 w = v * v;
        v2 e_elec = v * vfma(w, C1, onev);

        // e_vdw_raw in [-0.14,0] always -> grad path == clipped log path == ev
        v2 inv2 = inv * inv;
        v2 r2 = sigsq * inv2;
        v2 r6 = r2 * r2 * r2;
        v2 t126 = vfma(r6, r6, -r6);                // r12 - r6
        v2 ev = (lse * seP2) * t126;                // 4*eps_ij*(r12-r6)
        v2 addend = e_elec + ev;

        // dm = sigmoid((12-dist)*2); hsa = 1/(1+(ds/16)^2); shared rcp.
        // exp2 overflow -> A=inf -> r=0 -> dm=0 (correct limit, no NaN).
        v2 m = vfma(dist, K1, K2);
        v2 A; A.x = fexp2(m.x); A.y = fexp2(m.y);
        A = A + onev;
        v2 tq = ds * KQ;
        v2 Bh = vfma(tq, tq, onev);
        v2 AB = A * Bh;
        v2 r; r.x = frcp(AB.x); r.y = frcp(AB.y);
        v2 dm = Bh * r;

        s1v = vfma(addend, dm, s1v);
        s2v = vfma(lx0, r, s2v);
        v2 ov = __builtin_elementwise_max(vfma(sigma, KO, -dist), (v2)0.0f);
        s3v = vfma(ov, ov, s3v);
    }

    float s1 = s1v.x + s1v.y;
    float s2 = (s2v.x + s2v.y) * xP0;
    float s3 = s3v.x + s3v.y;

    #pragma unroll
    for (int off = 32; off > 0; off >>= 1) {
        s1 += __shfl_down(s1, off);
        s2 += __shfl_down(s2, off);
        s3 += __shfl_down(s3, off);
    }
    const int lane = tid & 63;
    const int wid  = tid >> 6;
    if (lane == 0) { red[wid][0] = s1; red[wid][1] = s2; red[wid][2] = s3; }
    __syncthreads();
    if (tid == 0) {
        float r0 = red[0][0] + red[1][0] + red[2][0] + red[3][0];
        float r1 = red[0][1] + red[1][1] + red[2][1] + red[3][1];
        float r2_ = red[0][2] + red[1][2] + red[2][2] + red[3][2];
        float* dst = partial + ((size_t)((b * CHUNKS + chunk) * LSPLIT + z)) * 4;
        dst[0] = r0; dst[1] = r1; dst[2] = r2_;
    }
}

// ---- kernel 3: finalize, 16 lanes per batch ----
__global__ __launch_bounds__(256) void physics_final(
    const float* __restrict__ partial, float* __restrict__ out)
{
    const int tid = threadIdx.x;
    if (tid == 0) out[2 * NB] = 2.0f;   // ALPHA
    const int b = tid >> 4;
    const int j = tid & 15;
    float s1 = 0.0f, s2 = 0.0f, s3 = 0.0f;
    const int NPART = CHUNKS * LSPLIT;   // 128 per batch
    #pragma unroll
    for (int k = 0; k < NPART / 16; ++k) {
        const float* src = partial + ((size_t)(b * NPART + j * (NPART / 16) + k)) * 4;
        s1 += src[0]; s2 += src[1]; s3 += src[2];
    }
    #pragma unroll
    for (int off = 8; off > 0; off >>= 1) {
        s1 += __shfl_down(s1, off, 16);
        s2 += __shfl_down(s2, off, 16);
        s3 += __shfl_down(s3, off, 16);
    }
    if (j == 0) {
        const float TG100 = 95.25741268224334f;   // sigmoid(3)*100
        float e_pauli = TG100 * s3;
        float e_hsa5  = -2.5f * s2;               // 5 * (-0.5 * S2)
        float e_raw = s1 + e_hsa5 + e_pauli;
        if (e_raw != e_raw) e_raw = 0.0f;
        float e_hard_log = fminf(e_pauli, 10000.0f);
        float e_soft_log = fminf(fmaxf(s1 + e_hsa5, -500.0f), 5000.0f);  // s4==s1
        float log_energy = fminf(e_soft_log + e_hard_log, 1000000.0f);
        out[b]              = e_raw;
        out[NB + b]         = e_hard_log;
        out[2 * NB + 1 + b] = log_energy;
    }
}

extern "C" void kernel_launch(void* const* d_in, const int* in_sizes, int n_in,
                              void* d_out, int out_size, void* d_ws, size_t ws_size,
                              hipStream_t stream)
{
    const float* pos_L = (const float*)d_in[0];
    const float* pos_P = (const float*)d_in[1];
    const float* q_L   = (const float*)d_in[2];
    const float* q_P   = (const float*)d_in[3];
    const float* x_L   = (const float*)d_in[4];
    const float* x_P   = (const float*)d_in[5];
    const float* vdw   = (const float*)d_in[6];
    const float* epst  = (const float*)d_in[7];
    float* out = (float*)d_out;

    float* ligbuf  = (float*)d_ws;                       // 16*64*16 floats = 64 KB
    float* partial = ligbuf + (size_t)NB * NPAIR * 16;   // 16*128*4 floats = 32 KB

    lig_prep<<<8, 256, 0, stream>>>(pos_L, q_L, x_L, vdw, epst, ligbuf);
    dim3 grid(CHUNKS, NB, LSPLIT);
    physics_main<<<grid, THREADS, 0, stream>>>(pos_P, q_P, x_P, ligbuf, partial);
    physics_final<<<1, 256, 0, stream>>>(partial, out);
}

// Round 6
// 88.266 us; speedup vs baseline: 1.2117x; 1.0343x over previous
//
#include <hip/hip_runtime.h>
#include <math.h>
#include <stdint.h>

#define NB 16
#define NL 128
#define NP 8192
#define CHUNKS 16        // 8192 / (256 threads * 2 atoms) protein chunks
#define THREADS 256
#define PPT 2            // protein atoms per thread (the v2 lanes)
#define LSPLIT 8         // ligand splits -> grid z
#define LPB 16           // ligands per block = 128/8

typedef float v2 __attribute__((ext_vector_type(2)));
typedef float v4 __attribute__((ext_vector_type(4)));
// constant address space -> scalar (SMEM) loads for uniform addresses
typedef const __attribute__((address_space(4))) v4* cv4p;

__device__ __forceinline__ float fexp2(float x) { return __builtin_amdgcn_exp2f(x); }
__device__ __forceinline__ float frcp(float x)  { return __builtin_amdgcn_rcpf(x); }
__device__ __forceinline__ float frsq(float x)  { return __builtin_amdgcn_rsqf(x); }
__device__ __forceinline__ float fsqrt_(float x){ return __builtin_amdgcn_sqrtf(x); }
__device__ __forceinline__ v2 vfma(v2 a, v2 b, v2 c) { return __builtin_elementwise_fma(a, b, c); }

// ---- kernel 1: ligand features, 32B records [px,py,pz,aq | rad,se4,x0,0] ----
__global__ __launch_bounds__(256) void lig_prep(
    const float* __restrict__ pos_L, const float* __restrict__ q_L,
    const float* __restrict__ x_L,
    const float* __restrict__ vdw_radii, const float* __restrict__ eps_tbl,
    float* __restrict__ ligbuf)
{
    const int id = blockIdx.x * 256 + threadIdx.x;
    if (id >= NB * NL) return;
    const int base = id;
    float px = pos_L[base * 3 + 0];
    float py = pos_L[base * 3 + 1];
    float pz = pos_L[base * 3 + 2];
    float aq = 83.015f * q_L[base];       // 332.06 / 4
    float rad = 0.0f, ep = 0.0f;
    #pragma unroll
    for (int j = 0; j < 9; ++j) {
        float v = x_L[base * 9 + j];
        rad = fmaf(v, vdw_radii[j], rad);
        ep  = fmaf(v, eps_tbl[j],  ep);
    }
    float se4 = 4.0f * fsqrt_(fmaxf(ep, 0.0f));   // 4*sqrt(relu(epsL))
    float x0  = x_L[base * 9 + 0];
    float4* dst = (float4*)(ligbuf + (size_t)base * 8);
    dst[0] = make_float4(px, py, pz, aq);
    dst[1] = make_float4(rad, se4, x0, 0.0f);
}

// ---- kernel 2: main loop. v2 lanes = 2 protein atoms per thread; ligand is
// wave-uniform scalar (SGPR) feeding v_pk ops. No LDS/barriers in loop. ----
__global__ __launch_bounds__(THREADS) void physics_main(
    const float* __restrict__ pos_P, const float* __restrict__ q_P,
    const float* __restrict__ x_P,   const float* __restrict__ ligbuf,
    float* __restrict__ partial)
{
    const int b     = blockIdx.y;
    const int chunk = blockIdx.x;
    const int z     = blockIdx.z;
    const int tid   = threadIdx.x;

    __shared__ float red[4][3];

    const int p0  = chunk * (THREADS * PPT) + tid;
    const int pb0 = b * NP + p0;
    const int pb1 = pb0 + THREADS;

    v2 ppx2; ppx2.x = pos_P[pb0 * 3 + 0]; ppx2.y = pos_P[pb1 * 3 + 0];
    v2 ppy2; ppy2.x = pos_P[pb0 * 3 + 1]; ppy2.y = pos_P[pb1 * 3 + 1];
    v2 ppz2; ppz2.x = pos_P[pb0 * 3 + 2]; ppz2.y = pos_P[pb1 * 3 + 2];
    v2 qP2;  qP2.x  = q_P[pb0];           qP2.y  = q_P[pb1];
    const float4 xp0 = ((const float4*)x_P)[pb0];
    const float4 xp1 = ((const float4*)x_P)[pb1];
    v2 rP2, seP2, xP02;
    rP2.x  = 1.7f * xp0.x + 1.55f * xp0.y + 1.52f * xp0.z + 1.8f * xp0.w;
    rP2.y  = 1.7f * xp1.x + 1.55f * xp1.y + 1.52f * xp1.z + 1.8f * xp1.w;
    seP2.x = fsqrt_(0.1f * xp0.x + 0.10f * xp0.y + 0.15f * xp0.z + 0.2f * xp0.w);
    seP2.y = fsqrt_(0.1f * xp1.x + 0.10f * xp1.y + 0.15f * xp1.z + 0.2f * xp1.w);
    xP02.x = xp0.x; xP02.y = xp1.x;

    const v2 onev = (v2)1.0f;
    const v2 C1 = (v2)(-8.3333333e-6f);   // 200*tanh(v/200) ~ v*(1 + C1*v^2)
    const v2 K1 = (v2)(2.8853901f);       // 2*log2(e)
    const v2 K2 = (v2)(-34.624681f);      // -24*log2(e)

    v2 s1v = (v2)0.0f, s2v = (v2)0.0f, s3v = (v2)0.0f;

    const float* lp = ligbuf + ((size_t)(b * NL + z * LPB)) * 8;
    cv4p Lc = (cv4p)(uintptr_t)lp;        // SMEM path

    #pragma unroll
    for (int i = 0; i < LPB; ++i) {
        const v4 A0 = Lc[i * 2 + 0];      // px,py,pz,aq   (SGPRs)
        const v4 A1 = Lc[i * 2 + 1];      // rad,se4,x0,-

        v2 dx = (v2)A0.x - ppx2;
        v2 dy = (v2)A0.y - ppy2;
        v2 dz = (v2)A0.z - ppz2;
        v2 ds = vfma(dx, dx, vfma(dy, dy, vfma(dz, dz, (v2)1e-8f)));
        v2 dist; dist.x = fsqrt_(ds.x); dist.y = fsqrt_(ds.y);

        v2 sigma = (v2)A1.x + rP2;
        v2 sigsq = sigma * sigma;
        v2 sd2 = vfma(sigsq, (v2)2.0f, ds);         // ds + 2*sigma^2
        v2 inv; inv.x = frsq(sd2.x); inv.y = frsq(sd2.y);

        // e_elec = 200*tanh(v/200) ~ v*(1 + C1*v^2); |v|<=32 -> err<=1.4e-3
        v2 v = ((v2)A0.w * qP2) * inv;
        v2 w = v * v;
        v2 e_elec = v * vfma(w, C1, onev);

        // e_vdw_raw in [-0.14,0] always -> grad path == clipped log path == ev
        v2 inv2 = inv * inv;
        v2 r2 = sigsq * inv2;
        v2 r6 = r2 * r2 * r2;
        v2 t126 = vfma(r6, r6, -r6);                // r12 - r6
        v2 ev = ((v2)A1.y * seP2) * t126;           // 4*eps_ij*(r12-r6)
        v2 addend = e_elec + ev;

        // dm = sigmoid((12-dist)*2); hsa = 1/(1+(ds/16)^2); shared rcp.
        // exp2 overflow -> A=inf -> rr=0 -> dm=0 (correct limit, no NaN).
        v2 m = vfma(dist, K1, K2);
        v2 A; A.x = fexp2(m.x); A.y = fexp2(m.y);
        A = A + onev;
        v2 tq = ds * 0.0625f;
        v2 Bh = vfma(tq, tq, onev);
        v2 AB = A * Bh;
        v2 rr; rr.x = frcp(AB.x); rr.y = frcp(AB.y);
        v2 dm = Bh * rr;

        s1v = vfma(addend, dm, s1v);
        s2v = vfma((v2)A1.z, rr, s2v);
        v2 ov = __builtin_elementwise_max(vfma(sigma, (v2)0.6f, -dist), (v2)0.0f);
        s3v = vfma(ov, ov, s3v);
    }

    v2 s2p = s2v * xP02;                  // per-atom xP0 weight
    float s1 = s1v.x + s1v.y;
    float s2 = s2p.x + s2p.y;
    float s3 = s3v.x + s3v.y;

    #pragma unroll
    for (int off = 32; off > 0; off >>= 1) {
        s1 += __shfl_down(s1, off);
        s2 += __shfl_down(s2, off);
        s3 += __shfl_down(s3, off);
    }
    const int lane = tid & 63;
    const int wid  = tid >> 6;
    if (lane == 0) { red[wid][0] = s1; red[wid][1] = s2; red[wid][2] = s3; }
    __syncthreads();
    if (tid == 0) {
        float r0 = red[0][0] + red[1][0] + red[2][0] + red[3][0];
        float r1 = red[0][1] + red[1][1] + red[2][1] + red[3][1];
        float r2_ = red[0][2] + red[1][2] + red[2][2] + red[3][2];
        float* dst = partial + ((size_t)((b * CHUNKS + chunk) * LSPLIT + z)) * 4;
        dst[0] = r0; dst[1] = r1; dst[2] = r2_;
    }
}

// ---- kernel 3: finalize, 16 lanes per batch ----
__global__ __launch_bounds__(256) void physics_final(
    const float* __restrict__ partial, float* __restrict__ out)
{
    const int tid = threadIdx.x;
    if (tid == 0) out[2 * NB] = 2.0f;   // ALPHA
    const int b = tid >> 4;
    const int j = tid & 15;
    float s1 = 0.0f, s2 = 0.0f, s3 = 0.0f;
    const int NPART = CHUNKS * LSPLIT;   // 128 per batch
    #pragma unroll
    for (int k = 0; k < NPART / 16; ++k) {
        const float* src = partial + ((size_t)(b * NPART + j * (NPART / 16) + k)) * 4;
        s1 += src[0]; s2 += src[1]; s3 += src[2];
    }
    #pragma unroll
    for (int off = 8; off > 0; off >>= 1) {
        s1 += __shfl_down(s1, off, 16);
        s2 += __shfl_down(s2, off, 16);
        s3 += __shfl_down(s3, off, 16);
    }
    if (j == 0) {
        const float TG100 = 95.25741268224334f;   // sigmoid(3)*100
        float e_pauli = TG100 * s3;
        float e_hsa5  = -2.5f * s2;               // 5 * (-0.5 * S2)
        float e_raw = s1 + e_hsa5 + e_pauli;
        if (e_raw != e_raw) e_raw = 0.0f;
        float e_hard_log = fminf(e_pauli, 10000.0f);
        float e_soft_log = fminf(fmaxf(s1 + e_hsa5, -500.0f), 5000.0f);  // s4==s1
        float log_energy = fminf(e_soft_log + e_hard_log, 1000000.0f);
        out[b]              = e_raw;
        out[NB + b]         = e_hard_log;
        out[2 * NB + 1 + b] = log_energy;
    }
}

extern "C" void kernel_launch(void* const* d_in, const int* in_sizes, int n_in,
                              void* d_out, int out_size, void* d_ws, size_t ws_size,
                              hipStream_t stream)
{
    const float* pos_L = (const float*)d_in[0];
    const float* pos_P = (const float*)d_in[1];
    const float* q_L   = (const float*)d_in[2];
    const float* q_P   = (const float*)d_in[3];
    const float* x_L   = (const float*)d_in[4];
    const float* x_P   = (const float*)d_in[5];
    const float* vdw   = (const float*)d_in[6];
    const float* epst  = (const float*)d_in[7];
    float* out = (float*)d_out;

    float* ligbuf  = (float*)d_ws;                      // 16*128*8 floats = 64 KB
    float* partial = ligbuf + (size_t)NB * NL * 8;      // 16*128*4 floats = 32 KB

    lig_prep<<<8, 256, 0, stream>>>(pos_L, q_L, x_L, vdw, epst, ligbuf);
    dim3 grid(CHUNKS, NB, LSPLIT);
    physics_main<<<grid, THREADS, 0, stream>>>(pos_P, q_P, x_P, ligbuf, partial);
    physics_final<<<1, 256, 0, stream>>>(partial, out);
}

// Round 7
// 87.443 us; speedup vs baseline: 1.2231x; 1.0094x over previous
//
#include <hip/hip_runtime.h>
#include <math.h>
#include <stdint.h>

#define NB 16
#define NL 128
#define NP 8192
#define THREADS 256
#define PPT 4            // protein atoms per thread (2 x v2 register blocks)
#define CHUNKS 8         // 8192 / (256 threads * 4 atoms)
#define LSPLIT 8         // ligand splits -> grid z
#define LPB 16           // ligands per block = 128/8

typedef float v2 __attribute__((ext_vector_type(2)));
typedef float v4 __attribute__((ext_vector_type(4)));
// constant address space -> scalar (SMEM) loads for uniform addresses
typedef const __attribute__((address_space(4))) v4* cv4p;

__device__ __forceinline__ float fexp2(float x) { return __builtin_amdgcn_exp2f(x); }
__device__ __forceinline__ float frcp(float x)  { return __builtin_amdgcn_rcpf(x); }
__device__ __forceinline__ float frsq(float x)  { return __builtin_amdgcn_rsqf(x); }
__device__ __forceinline__ float fsqrt_(float x){ return __builtin_amdgcn_sqrtf(x); }
__device__ __forceinline__ v2 vfma(v2 a, v2 b, v2 c) { return __builtin_elementwise_fma(a, b, c); }

// ---- kernel 1: ligand features, 32B records [px,py,pz,aq | rad,se4,x0,0] ----
__global__ __launch_bounds__(256) void lig_prep(
    const float* __restrict__ pos_L, const float* __restrict__ q_L,
    const float* __restrict__ x_L,
    const float* __restrict__ vdw_radii, const float* __restrict__ eps_tbl,
    float* __restrict__ ligbuf)
{
    const int id = blockIdx.x * 256 + threadIdx.x;
    if (id >= NB * NL) return;
    const int base = id;
    float px = pos_L[base * 3 + 0];
    float py = pos_L[base * 3 + 1];
    float pz = pos_L[base * 3 + 2];
    float aq = 83.015f * q_L[base];       // 332.06 / 4
    float rad = 0.0f, ep = 0.0f;
    #pragma unroll
    for (int j = 0; j < 9; ++j) {
        float v = x_L[base * 9 + j];
        rad = fmaf(v, vdw_radii[j], rad);
        ep  = fmaf(v, eps_tbl[j],  ep);
    }
    float se4 = 4.0f * fsqrt_(fmaxf(ep, 0.0f));   // 4*sqrt(relu(epsL))
    float x0  = x_L[base * 9 + 0];
    float4* dst = (float4*)(ligbuf + (size_t)base * 8);
    dst[0] = make_float4(px, py, pz, aq);
    dst[1] = make_float4(rad, se4, x0, 0.0f);
}

// one v2 block (2 protein atoms) worth of per-pair physics
struct PState {
    v2 ppx, ppy, ppz, qP, rP, seP, xP0;
    v2 s1, s2, s3;
};

__device__ __forceinline__ void pair_step(PState& S, const v4 A0, const v4 A1)
{
    const v2 onev = (v2)1.0f;
    const v2 C1 = (v2)(-8.3333333e-6f);   // 200*tanh(v/200) ~ v*(1 + C1*v^2)
    const v2 K1 = (v2)(2.8853901f);       // 2*log2(e)
    const v2 K2 = (v2)(-34.624681f);      // -24*log2(e)

    v2 dx = (v2)A0.x - S.ppx;
    v2 dy = (v2)A0.y - S.ppy;
    v2 dz = (v2)A0.z - S.ppz;
    v2 ds = vfma(dx, dx, vfma(dy, dy, vfma(dz, dz, (v2)1e-8f)));
    v2 dist; dist.x = fsqrt_(ds.x); dist.y = fsqrt_(ds.y);

    v2 sigma = (v2)A1.x + S.rP;
    v2 sigsq = sigma * sigma;
    v2 sd2 = vfma(sigsq, (v2)2.0f, ds);           // ds + 2*sigma^2
    v2 inv; inv.x = frsq(sd2.x); inv.y = frsq(sd2.y);

    // e_elec = 200*tanh(v/200) ~ v*(1 + C1*v^2); |v|<=32 -> err<=1.4e-3
    v2 v = ((v2)A0.w * S.qP) * inv;
    v2 w = v * v;
    v2 e_elec = v * vfma(w, C1, onev);

    // e_vdw_raw in [-0.14,0] always -> grad path == clipped log path == ev
    v2 inv2 = inv * inv;
    v2 r2 = sigsq * inv2;
    v2 r6 = r2 * r2 * r2;
    v2 t126 = vfma(r6, r6, -r6);                  // r12 - r6
    v2 ev = ((v2)A1.y * S.seP) * t126;            // 4*eps_ij*(r12-r6)
    v2 addend = e_elec + ev;

    // dm = sigmoid((12-dist)*2); hsa = 1/(1+(ds/16)^2); shared rcp.
    // exp2 overflow -> A=inf -> rr=0 -> dm=0 (correct limit, no NaN).
    v2 m = vfma(dist, K1, K2);
    v2 A; A.x = fexp2(m.x); A.y = fexp2(m.y);
    A = A + onev;
    v2 tq = ds * 0.0625f;
    v2 Bh = vfma(tq, tq, onev);
    v2 AB = A * Bh;
    v2 rr; rr.x = frcp(AB.x); rr.y = frcp(AB.y);
    v2 dm = Bh * rr;

    S.s1 = vfma(addend, dm, S.s1);
    S.s2 = vfma((v2)A1.z, rr, S.s2);
    v2 ov = __builtin_elementwise_max(vfma(sigma, (v2)0.6f, -dist), (v2)0.0f);
    S.s3 = vfma(ov, ov, S.s3);
}

__device__ __forceinline__ void load_pstate(
    PState& S, const float* pos_P, const float* q_P, const float* x_P,
    int pb0, int stride)
{
    const int pbA = pb0, pbB = pb0 + stride;
    S.ppx.x = pos_P[pbA * 3 + 0]; S.ppx.y = pos_P[pbB * 3 + 0];
    S.ppy.x = pos_P[pbA * 3 + 1]; S.ppy.y = pos_P[pbB * 3 + 1];
    S.ppz.x = pos_P[pbA * 3 + 2]; S.ppz.y = pos_P[pbB * 3 + 2];
    S.qP.x  = q_P[pbA];           S.qP.y  = q_P[pbB];
    const float4 xa = ((const float4*)x_P)[pbA];
    const float4 xb = ((const float4*)x_P)[pbB];
    S.rP.x  = 1.7f * xa.x + 1.55f * xa.y + 1.52f * xa.z + 1.8f * xa.w;
    S.rP.y  = 1.7f * xb.x + 1.55f * xb.y + 1.52f * xb.z + 1.8f * xb.w;
    S.seP.x = fsqrt_(0.1f * xa.x + 0.10f * xa.y + 0.15f * xa.z + 0.2f * xa.w);
    S.seP.y = fsqrt_(0.1f * xb.x + 0.10f * xb.y + 0.15f * xb.z + 0.2f * xb.w);
    S.xP0.x = xa.x; S.xP0.y = xb.x;
    S.s1 = (v2)0.0f; S.s2 = (v2)0.0f; S.s3 = (v2)0.0f;
}

// ---- kernel 2: main loop; 4 protein atoms/thread, ligand via SMEM scalar ----
__global__ __launch_bounds__(THREADS, 4) void physics_main(
    const float* __restrict__ pos_P, const float* __restrict__ q_P,
    const float* __restrict__ x_P,   const float* __restrict__ ligbuf,
    float* __restrict__ partial)
{
    const int b     = blockIdx.y;
    const int chunk = blockIdx.x;
    const int z     = blockIdx.z;
    const int tid   = threadIdx.x;

    __shared__ float red[4][3];

    const int p0  = chunk * (THREADS * PPT) + tid;
    const int pb0 = b * NP + p0;

    PState SA, SB;
    load_pstate(SA, pos_P, q_P, x_P, pb0,               THREADS);
    load_pstate(SB, pos_P, q_P, x_P, pb0 + 2 * THREADS, THREADS);

    const float* lp = ligbuf + ((size_t)(b * NL + z * LPB)) * 8;
    cv4p Lc = (cv4p)(uintptr_t)lp;        // SMEM path

    #pragma unroll 4
    for (int i = 0; i < LPB; ++i) {
        const v4 A0 = Lc[i * 2 + 0];      // px,py,pz,aq   (SGPRs)
        const v4 A1 = Lc[i * 2 + 1];      // rad,se4,x0,-
        pair_step(SA, A0, A1);
        pair_step(SB, A0, A1);
    }

    v2 s2pA = SA.s2 * SA.xP0;
    v2 s2pB = SB.s2 * SB.xP0;
    float s1 = SA.s1.x + SA.s1.y + SB.s1.x + SB.s1.y;
    float s2 = s2pA.x + s2pA.y + s2pB.x + s2pB.y;
    float s3 = SA.s3.x + SA.s3.y + SB.s3.x + SB.s3.y;

    #pragma unroll
    for (int off = 32; off > 0; off >>= 1) {
        s1 += __shfl_down(s1, off);
        s2 += __shfl_down(s2, off);
        s3 += __shfl_down(s3, off);
    }
    const int lane = tid & 63;
    const int wid  = tid >> 6;
    if (lane == 0) { red[wid][0] = s1; red[wid][1] = s2; red[wid][2] = s3; }
    __syncthreads();
    if (tid == 0) {
        float r0 = red[0][0] + red[1][0] + red[2][0] + red[3][0];
        float r1 = red[0][1] + red[1][1] + red[2][1] + red[3][1];
        float r2_ = red[0][2] + red[1][2] + red[2][2] + red[3][2];
        float* dst = partial + ((size_t)((b * CHUNKS + chunk) * LSPLIT + z)) * 4;
        dst[0] = r0; dst[1] = r1; dst[2] = r2_;
    }
}

// ---- kernel 3: finalize, 8 lanes per batch (128 partials/batch) ----
__global__ __launch_bounds__(256) void physics_final(
    const float* __restrict__ partial, float* __restrict__ out)
{
    const int tid = threadIdx.x;
    if (tid == 0) out[2 * NB] = 2.0f;   // ALPHA
    const int b = tid >> 4;
    const int j = tid & 15;
    if (b >= NB) return;
    float s1 = 0.0f, s2 = 0.0f, s3 = 0.0f;
    const int NPART = CHUNKS * LSPLIT;   // 64 per batch
    #pragma unroll
    for (int k = 0; k < NPART / 16; ++k) {
        const float* src = partial + ((size_t)(b * NPART + j * (NPART / 16) + k)) * 4;
        s1 += src[0]; s2 += src[1]; s3 += src[2];
    }
    #pragma unroll
    for (int off = 8; off > 0; off >>= 1) {
        s1 += __shfl_down(s1, off, 16);
        s2 += __shfl_down(s2, off, 16);
        s3 += __shfl_down(s3, off, 16);
    }
    if (j == 0) {
        const float TG100 = 95.25741268224334f;   // sigmoid(3)*100
        float e_pauli = TG100 * s3;
        float e_hsa5  = -2.5f * s2;               // 5 * (-0.5 * S2)
        float e_raw = s1 + e_hsa5 + e_pauli;
        if (e_raw != e_raw) e_raw = 0.0f;
        float e_hard_log = fminf(e_pauli, 10000.0f);
        float e_soft_log = fminf(fmaxf(s1 + e_hsa5, -500.0f), 5000.0f);  // s4==s1
        float log_energy = fminf(e_soft_log + e_hard_log, 1000000.0f);
        out[b]              = e_raw;
        out[NB + b]         = e_hard_log;
        out[2 * NB + 1 + b] = log_energy;
    }
}

extern "C" void kernel_launch(void* const* d_in, const int* in_sizes, int n_in,
                              void* d_out, int out_size, void* d_ws, size_t ws_size,
                              hipStream_t stream)
{
    const float* pos_L = (const float*)d_in[0];
    const float* pos_P = (const float*)d_in[1];
    const float* q_L   = (const float*)d_in[2];
    const float* q_P   = (const float*)d_in[3];
    const float* x_L   = (const float*)d_in[4];
    const float* x_P   = (const float*)d_in[5];
    const float* vdw   = (const float*)d_in[6];
    const float* epst  = (const float*)d_in[7];
    float* out = (float*)d_out;

    float* ligbuf  = (float*)d_ws;                      // 16*128*8 floats = 64 KB
    float* partial = ligbuf + (size_t)NB * NL * 8;      // 16*64*4 floats = 16 KB

    lig_prep<<<8, 256, 0, stream>>>(pos_L, q_L, x_L, vdw, epst, ligbuf);
    dim3 grid(CHUNKS, NB, LSPLIT);
    physics_main<<<grid, THREADS, 0, stream>>>(pos_P, q_P, x_P, ligbuf, partial);
    physics_final<<<1, 256, 0, stream>>>(partial, out);
}

// Round 8
// 86.826 us; speedup vs baseline: 1.2318x; 1.0071x over previous
//
#include <hip/hip_runtime.h>
#include <math.h>
#include <stdint.h>

#define NB 16
#define NL 128
#define NP 8192
#define THREADS 256
#define PPT 4            // protein atoms per thread (2 x v2 register blocks)
#define CHUNKS 8         // 8192 / (256 threads * 4 atoms)
#define LSPLIT 8         // ligand splits -> grid z
#define LPB 16           // ligands per block = 128/8

typedef float v2 __attribute__((ext_vector_type(2)));

__device__ __forceinline__ float fexp2(float x) { return __builtin_amdgcn_exp2f(x); }
__device__ __forceinline__ float frcp(float x)  { return __builtin_amdgcn_rcpf(x); }
__device__ __forceinline__ float frsq(float x)  { return __builtin_amdgcn_rsqf(x); }
__device__ __forceinline__ float fsqrt_(float x){ return __builtin_amdgcn_sqrtf(x); }
__device__ __forceinline__ v2 vfma(v2 a, v2 b, v2 c) { return __builtin_elementwise_fma(a, b, c); }

// one v2 block (2 protein atoms) of per-pair physics state
struct PState {
    v2 ppx, ppy, ppz, qP, rP, seP, xP0;
    v2 s1, s2, s3;
};

__device__ __forceinline__ void pair_step(PState& S, const float4 A0, const float4 A1)
{
    const v2 onev = (v2)1.0f;
    const v2 C1 = (v2)(-8.3333333e-6f);   // 200*tanh(v/200) ~ v*(1 + C1*v^2)
    const v2 K1 = (v2)(2.8853901f);       // 2*log2(e)
    const v2 K2 = (v2)(-34.624681f);      // -24*log2(e)

    v2 dx = (v2)A0.x - S.ppx;
    v2 dy = (v2)A0.y - S.ppy;
    v2 dz = (v2)A0.z - S.ppz;
    v2 ds = vfma(dx, dx, vfma(dy, dy, vfma(dz, dz, (v2)1e-8f)));
    v2 dist; dist.x = fsqrt_(ds.x); dist.y = fsqrt_(ds.y);

    v2 sigma = (v2)A1.x + S.rP;
    v2 sigsq = sigma * sigma;
    v2 sd2 = vfma(sigsq, (v2)2.0f, ds);           // ds + 2*sigma^2
    v2 inv; inv.x = frsq(sd2.x); inv.y = frsq(sd2.y);

    // e_elec = 200*tanh(v/200) ~ v*(1 + C1*v^2); |v|<=32 -> err<=1.4e-3
    v2 v = ((v2)A0.w * S.qP) * inv;
    v2 w = v * v;
    v2 e_elec = v * vfma(w, C1, onev);

    // e_vdw_raw in [-0.14,0] always -> grad path == clipped log path == ev
    v2 inv2 = inv * inv;
    v2 r2 = sigsq * inv2;
    v2 r6 = r2 * r2 * r2;
    v2 t126 = vfma(r6, r6, -r6);                  // r12 - r6
    v2 ev = ((v2)A1.y * S.seP) * t126;            // 4*eps_ij*(r12-r6)
    v2 addend = e_elec + ev;

    // dm = sigmoid((12-dist)*2); hsa = 1/(1+(ds/16)^2); shared rcp.
    // exp2 overflow -> A=inf -> rr=0 -> dm=0 (correct limit, no NaN).
    v2 m = vfma(dist, K1, K2);
    v2 A; A.x = fexp2(m.x); A.y = fexp2(m.y);
    A = A + onev;
    v2 tq = ds * 0.0625f;
    v2 Bh = vfma(tq, tq, onev);
    v2 AB = A * Bh;
    v2 rr; rr.x = frcp(AB.x); rr.y = frcp(AB.y);
    v2 dm = Bh * rr;

    S.s1 = vfma(addend, dm, S.s1);
    S.s2 = vfma((v2)A1.z, rr, S.s2);
    v2 ov = __builtin_elementwise_max(vfma(sigma, (v2)0.6f, -dist), (v2)0.0f);
    S.s3 = vfma(ov, ov, S.s3);
}

__device__ __forceinline__ void load_pstate(
    PState& S, const float* pos_P, const float* q_P, const float* x_P,
    int pb0, int stride)
{
    const int pbA = pb0, pbB = pb0 + stride;
    S.ppx.x = pos_P[pbA * 3 + 0]; S.ppx.y = pos_P[pbB * 3 + 0];
    S.ppy.x = pos_P[pbA * 3 + 1]; S.ppy.y = pos_P[pbB * 3 + 1];
    S.ppz.x = pos_P[pbA * 3 + 2]; S.ppz.y = pos_P[pbB * 3 + 2];
    S.qP.x  = q_P[pbA];           S.qP.y  = q_P[pbB];
    const float4 xa = ((const float4*)x_P)[pbA];
    const float4 xb = ((const float4*)x_P)[pbB];
    S.rP.x  = 1.7f * xa.x + 1.55f * xa.y + 1.52f * xa.z + 1.8f * xa.w;
    S.rP.y  = 1.7f * xb.x + 1.55f * xb.y + 1.52f * xb.z + 1.8f * xb.w;
    S.seP.x = fsqrt_(0.1f * xa.x + 0.10f * xa.y + 0.15f * xa.z + 0.2f * xa.w);
    S.seP.y = fsqrt_(0.1f * xb.x + 0.10f * xb.y + 0.15f * xb.z + 0.2f * xb.w);
    S.xP0.x = xa.x; S.xP0.y = xb.x;
    S.s1 = (v2)0.0f; S.s2 = (v2)0.0f; S.s3 = (v2)0.0f;
}

// ---- kernel 1: fused ligand prep (per-block, redundant, trivial) + main loop ----
__global__ __launch_bounds__(THREADS, 4) void physics_main(
    const float* __restrict__ pos_L, const float* __restrict__ pos_P,
    const float* __restrict__ q_L,   const float* __restrict__ q_P,
    const float* __restrict__ x_L,   const float* __restrict__ x_P,
    const float* __restrict__ vdw_radii, const float* __restrict__ eps_tbl,
    float* __restrict__ partial)
{
    const int b     = blockIdx.y;
    const int chunk = blockIdx.x;
    const int z     = blockIdx.z;
    const int tid   = threadIdx.x;

    // ligand tile: [i][0]=(px,py,pz,aq)  [i][1]=(rad,se4,x0,0)
    __shared__ float4 lig[LPB][2];
    __shared__ float red[4][3];

    if (tid < LPB) {
        const int base = b * NL + z * LPB + tid;
        float px = pos_L[base * 3 + 0];
        float py = pos_L[base * 3 + 1];
        float pz = pos_L[base * 3 + 2];
        float aq = 83.015f * q_L[base];       // 332.06 / 4
        float rad = 0.0f, ep = 0.0f;
        #pragma unroll
        for (int j = 0; j < 9; ++j) {
            float v = x_L[base * 9 + j];
            rad = fmaf(v, vdw_radii[j], rad);
            ep  = fmaf(v, eps_tbl[j],  ep);
        }
        float se4 = 4.0f * fsqrt_(fmaxf(ep, 0.0f));   // 4*sqrt(relu(epsL))
        float x0  = x_L[base * 9 + 0];
        lig[tid][0] = make_float4(px, py, pz, aq);
        lig[tid][1] = make_float4(rad, se4, x0, 0.0f);
    }

    const int p0  = chunk * (THREADS * PPT) + tid;
    const int pb0 = b * NP + p0;

    PState SA, SB;
    load_pstate(SA, pos_P, q_P, x_P, pb0,               THREADS);
    load_pstate(SB, pos_P, q_P, x_P, pb0 + 2 * THREADS, THREADS);

    __syncthreads();

    #pragma unroll 4
    for (int i = 0; i < LPB; ++i) {
        const float4 A0 = lig[i][0];      // uniform LDS -> broadcast
        const float4 A1 = lig[i][1];
        pair_step(SA, A0, A1);
        pair_step(SB, A0, A1);
    }

    v2 s2pA = SA.s2 * SA.xP0;
    v2 s2pB = SB.s2 * SB.xP0;
    float s1 = SA.s1.x + SA.s1.y + SB.s1.x + SB.s1.y;
    float s2 = s2pA.x + s2pA.y + s2pB.x + s2pB.y;
    float s3 = SA.s3.x + SA.s3.y + SB.s3.x + SB.s3.y;

    #pragma unroll
    for (int off = 32; off > 0; off >>= 1) {
        s1 += __shfl_down(s1, off);
        s2 += __shfl_down(s2, off);
        s3 += __shfl_down(s3, off);
    }
    const int lane = tid & 63;
    const int wid  = tid >> 6;
    if (lane == 0) { red[wid][0] = s1; red[wid][1] = s2; red[wid][2] = s3; }
    __syncthreads();
    if (tid == 0) {
        float r0 = red[0][0] + red[1][0] + red[2][0] + red[3][0];
        float r1 = red[0][1] + red[1][1] + red[2][1] + red[3][1];
        float r2_ = red[0][2] + red[1][2] + red[2][2] + red[3][2];
        float* dst = partial + ((size_t)((b * CHUNKS + chunk) * LSPLIT + z)) * 4;
        dst[0] = r0; dst[1] = r1; dst[2] = r2_;
    }
}

// ---- kernel 2: finalize, 16 lanes per batch (64 partials/batch) ----
__global__ __launch_bounds__(256) void physics_final(
    const float* __restrict__ partial, float* __restrict__ out)
{
    const int tid = threadIdx.x;
    if (tid == 0) out[2 * NB] = 2.0f;   // ALPHA
    const int b = tid >> 4;
    const int j = tid & 15;
    float s1 = 0.0f, s2 = 0.0f, s3 = 0.0f;
    const int NPART = CHUNKS * LSPLIT;   // 64 per batch
    #pragma unroll
    for (int k = 0; k < NPART / 16; ++k) {
        const float* src = partial + ((size_t)(b * NPART + j * (NPART / 16) + k)) * 4;
        s1 += src[0]; s2 += src[1]; s3 += src[2];
    }
    #pragma unroll
    for (int off = 8; off > 0; off >>= 1) {
        s1 += __shfl_down(s1, off, 16);
        s2 += __shfl_down(s2, off, 16);
        s3 += __shfl_down(s3, off, 16);
    }
    if (j == 0) {
        const float TG100 = 95.25741268224334f;   // sigmoid(3)*100
        float e_pauli = TG100 * s3;
        float e_hsa5  = -2.5f * s2;               // 5 * (-0.5 * S2)
        float e_raw = s1 + e_hsa5 + e_pauli;
        if (e_raw != e_raw) e_raw = 0.0f;
        float e_hard_log = fminf(e_pauli, 10000.0f);
        float e_soft_log = fminf(fmaxf(s1 + e_hsa5, -500.0f), 5000.0f);  // s4==s1
        float log_energy = fminf(e_soft_log + e_hard_log, 1000000.0f);
        out[b]              = e_raw;
        out[NB + b]         = e_hard_log;
        out[2 * NB + 1 + b] = log_energy;
    }
}

extern "C" void kernel_launch(void* const* d_in, const int* in_sizes, int n_in,
                              void* d_out, int out_size, void* d_ws, size_t ws_size,
                              hipStream_t stream)
{
    const float* pos_L = (const float*)d_in[0];
    const float* pos_P = (const float*)d_in[1];
    const float* q_L   = (const float*)d_in[2];
    const float* q_P   = (const float*)d_in[3];
    const float* x_L   = (const float*)d_in[4];
    const float* x_P   = (const float*)d_in[5];
    const float* vdw   = (const float*)d_in[6];
    const float* epst  = (const float*)d_in[7];
    float* out = (float*)d_out;
    float* partial = (float*)d_ws;     // 16*64*4 floats = 16 KB

    dim3 grid(CHUNKS, NB, LSPLIT);
    physics_main<<<grid, THREADS, 0, stream>>>(pos_L, pos_P, q_L, q_P, x_L, x_P,
                                               vdw, epst, partial);
    physics_final<<<1, 256, 0, stream>>>(partial, out);
}